// Round 9
// baseline (3379.577 us; speedup 1.0000x reference)
//
#include <hip/hip_runtime.h>
#include <hip/hip_bf16.h>
#include <hip/hip_fp16.h>

#define FEAT 128

typedef __attribute__((ext_vector_type(8))) short short8;
typedef __attribute__((ext_vector_type(4))) float f32x4;

static __device__ __forceinline__ unsigned short f2bf(float f) {
    unsigned int u = __float_as_uint(f);
    unsigned int r = (u + 0x7fffu + ((u >> 16) & 1u)) >> 16;
    return (unsigned short)r;
}
static __device__ __forceinline__ float bf2f(unsigned short b) {
    return __uint_as_float(((unsigned int)b) << 16);
}

// ---- CSR build -------------------------------------------------------------
// Round-15: edge-centric agg consumes the bucket-strided packed edges (tmp)
// DIRECTLY, so the compaction stage (bscan + bucket_fill2 + ssrc + indptr) is
// deleted. Pipeline: binit -> bucket_scatter -> dinv_wprep -> [gemm,agg]x3.
// tmp is now persistent (dedicated 9.6 MB, BCAP=3072 = mean+22sigma).

#define BKT_SHIFT 7
#define BKT_G 128
#define MAX_NB 1024
#define BCAP 3072
#define SC_T 32
#define SC_EPB (256 * SC_T)   // 8192 edges per block

__global__ void binit_kernel(int* __restrict__ bcur, int NB) {
    int b = blockIdx.x * 256 + threadIdx.x;
    if (b < NB) bcur[b] = b * BCAP;
}

__global__ __launch_bounds__(256)
void bucket_scatter_kernel(const int* __restrict__ src, const int* __restrict__ dst,
                           int* __restrict__ bcur, unsigned int* __restrict__ tmp,
                           int E, int NB) {
    __shared__ int hist[MAX_NB];
    const int tid = threadIdx.x;
    const int ebase = blockIdx.x * SC_EPB;

    for (int i = tid; i < NB; i += 256) hist[i] = 0;
    __syncthreads();

    unsigned int pk[SC_T];    // packed (src,dst_local)
    unsigned int meta[SC_T];  // (bucket<<16) | local_rank ; 0xFFFFFFFF = invalid
    #pragma unroll
    for (int j = 0; j < SC_T; ++j) {
        int e = ebase + j * 256 + tid;
        if (e < E) {
            int s = src[e], d = dst[e];
            int b = d >> BKT_SHIFT;
            pk[j] = ((unsigned int)s << BKT_SHIFT) | (unsigned int)(d & (BKT_G - 1));
            int r = atomicAdd(&hist[b], 1);
            meta[j] = ((unsigned int)b << 16) | (unsigned int)r;
        } else {
            meta[j] = 0xFFFFFFFFu;
        }
    }
    __syncthreads();

    // one global atomic per (block,bucket); stash base back into hist
    for (int b = tid; b < NB; b += 256) {
        int c = hist[b];
        if (c > 0) hist[b] = atomicAdd(&bcur[b], c);
    }
    __syncthreads();

    #pragma unroll
    for (int j = 0; j < SC_T; ++j) {
        if (meta[j] != 0xFFFFFFFFu) {
            int b = meta[j] >> 16;
            int r = (int)(meta[j] & 0xFFFFu);
            tmp[hist[b] + r] = pk[j];
        }
    }
}

// blocks [0,NB): per-bucket LDS histogram of tmp -> dinv.
// blocks [NB,NB+192): weight prep (transpose + bf16 hi/lo split).
__global__ __launch_bounds__(256)
void dinv_wprep_kernel(const int* __restrict__ bcur, const unsigned int* __restrict__ tmp,
                       float* __restrict__ dinv, int n, int NB,
                       const float* __restrict__ W1, const float* __restrict__ W2,
                       const float* __restrict__ W3, unsigned short* __restrict__ wth,
                       unsigned short* __restrict__ wtl) {
    const int tid = threadIdx.x;
    if ((int)blockIdx.x < NB) {
        const int b = blockIdx.x;
        __shared__ int hist[BKT_G];
        if (tid < BKT_G) hist[tid] = 0;
        __syncthreads();
        const int scnt = bcur[b] - b * BCAP;
        const unsigned int* tp = tmp + (size_t)b * BCAP;
        for (int e = tid; e < scnt; e += 256)
            atomicAdd(&hist[tp[e] & (BKT_G - 1)], 1);
        __syncthreads();
        if (tid < BKT_G) {
            int node = b * BKT_G + tid;
            if (node < n) dinv[node] = rsqrtf((float)(hist[tid] + 1));
        }
    } else {
        int idx = ((int)blockIdx.x - NB) * 256 + tid;   // 3 * 16384 total
        if (idx < 3 * 16384) {
            int l = idx >> 14, t = idx & 16383;
            int nn = t >> 7, kk = t & 127;
            const float* W = (l == 0) ? W1 : (l == 1) ? W2 : W3;
            float v = W[kk * 128 + nn];
            unsigned short h = f2bf(v);
            wth[idx] = h;
            wtl[idx] = f2bf(v - bf2f(h));
        }
    }
}

// ---- GEMM (split-bf16 MFMA, B staged in LDS): hs = (in @ W) * dinv ---------
// hs and the bf16 activation planes are FEATURE-SLICED: 8 slices of 16
// features; slice s of hs = hs + s*n*16 halfs (3.2 MB < 4 MB per-XCD L2).
// 128-row M-tile, 512 threads, layer 1 reads f32 x directly (in-reg split).

template <bool F32IN>
__global__ __launch_bounds__(512)
void gemm_mfma(const float* __restrict__ xf, const unsigned short* __restrict__ xh,
               const unsigned short* __restrict__ xl,
               const unsigned short* __restrict__ wth, const unsigned short* __restrict__ wtl,
               const float* __restrict__ dinv, __half* __restrict__ hs, int n) {
    __shared__ unsigned short bh[128][136];
    __shared__ unsigned short bl[128][136];

    const int tid = threadIdx.x;
    const int wave = tid >> 6, lane = tid & 63;
    const int rowbase = blockIdx.x * 128 + wave * 16;
    const int m = lane & 15, kg = lane >> 4;

    // stage B: 512 threads, 128 B each. plane p = tid>>8 (0=hi,1=lo)
    {
        const int p = tid >> 8, t = tid & 255;
        const int n0 = t >> 1, kk0 = (t & 1) * 64;
        const unsigned short* g = (p ? wtl : wth) + (size_t)n0 * FEAT + kk0;
        unsigned short (*dstp)[136] = p ? bl : bh;
        #pragma unroll
        for (int j = 0; j < 8; ++j)
            *(short8*)&dstp[n0][kk0 + j * 8] = *(const short8*)(g + j * 8);
    }

    // A fragments (loaded while staging is in flight)
    int arow = rowbase + m;
    if (arow > n - 1) arow = n - 1;          // clamp; clamped rows never stored
    short8 avh[4], avl[4];
    if constexpr (F32IN) {
        const float* ap = xf + (size_t)arow * FEAT + kg * 8;
        #pragma unroll
        for (int s = 0; s < 4; ++s) {
            float4 f0 = *(const float4*)(ap + s * 32);
            float4 f1 = *(const float4*)(ap + s * 32 + 4);
            float fv[8] = {f0.x, f0.y, f0.z, f0.w, f1.x, f1.y, f1.z, f1.w};
            short8 h, l;
            #pragma unroll
            for (int k = 0; k < 8; ++k) {
                unsigned short hb = f2bf(fv[k]);
                h[k] = (short)hb;
                l[k] = (short)f2bf(fv[k] - bf2f(hb));
            }
            avh[s] = h; avl[s] = l;
        }
    } else {
        // sliced planes: features kg*8 + s*32 -> slice s*2 + (kg>>1), off (kg&1)*8
        #pragma unroll
        for (int s = 0; s < 4; ++s) {
            const size_t po = ((size_t)(s * 2 + (kg >> 1)) * n + arow) * 16 + (kg & 1) * 8;
            avh[s] = *(const short8*)(xh + po);
            avl[s] = *(const short8*)(xl + po);
        }
    }

    __syncthreads();

    f32x4 acc[8];
    #pragma unroll
    for (int t = 0; t < 8; ++t) acc[t] = (f32x4){0.f, 0.f, 0.f, 0.f};

    #pragma unroll 2
    for (int t = 0; t < 8; ++t) {
        #pragma unroll
        for (int s = 0; s < 4; ++s) {
            short8 bvh = *(const short8*)&bh[t * 16 + m][s * 32 + kg * 8];
            short8 bvl = *(const short8*)&bl[t * 16 + m][s * 32 + kg * 8];
            acc[t] = __builtin_amdgcn_mfma_f32_16x16x32_bf16(avh[s], bvh, acc[t], 0, 0, 0);
            acc[t] = __builtin_amdgcn_mfma_f32_16x16x32_bf16(avh[s], bvl, acc[t], 0, 0, 0);
            acc[t] = __builtin_amdgcn_mfma_f32_16x16x32_bf16(avl[s], bvh, acc[t], 0, 0, 0);
        }
    }

    const int col = lane & 15, rb = (lane >> 4) * 4;
    #pragma unroll
    for (int r = 0; r < 4; ++r) {
        int row = rowbase + rb + r;
        if (row < n) {
            float d = dinv[row];
            #pragma unroll
            for (int t = 0; t < 8; ++t)
                hs[((size_t)t * n + row) * 16 + col] = __float2half(acc[t][r] * d);
        }
    }
}

// ---- aggregation: out = act( dinv[i]*(hs[i] + sum hs[src]) + b ) -----------
// Round-15: edge-centric, divergence-free. Block = (bucket, slice); slice =
// blockIdx.x & 7 for XCD L2 affinity (3.2 MB slice resident — r8 proved the
// FETCH drop). Stage 256 packed edges in LDS; each 8-lane group processes 8
// edges with batched independent 32 B gathers, accumulating via LDS f32
// atomics into acc[128][17] (pad kills the even-bank conflict). Epilogue adds
// self row, scales, bias, relu, writes sliced planes / final f32.

__global__ __launch_bounds__(256)
void agg_kernel(const __half* __restrict__ hs, const unsigned int* __restrict__ tmp,
                const int* __restrict__ bcur, const float* __restrict__ dinv,
                const float* __restrict__ bias, float* __restrict__ outf,
                unsigned short* __restrict__ outh, unsigned short* __restrict__ outl,
                int n, int do_relu) {
    const int tid = threadIdx.x;
    const int slice = blockIdx.x & 7;
    const int b = blockIdx.x >> 3;
    const int grp = tid >> 3, fl = tid & 7;

    __shared__ float acc[BKT_G][17];
    __shared__ unsigned int eb[256];

    #pragma unroll
    for (int i = 0; i < 8; ++i) {
        int idx = i * 256 + tid;            // 2048 of 2176 slots; pad cols stay junk
        acc[idx >> 4 & 127][(idx & 15)] = 0.f;
    }
    // zero via linear walk over the used 16 columns only:
    // (rewritten safely below)
    __syncthreads();
    // re-zero properly (the above covers rows 0..127 cols 0..15 exactly:
    // idx>>4 in [0,128), idx&15 in [0,16)) -- correct.

    const int scnt = bcur[b] - b * BCAP;
    const unsigned int* tp = tmp + (size_t)b * BCAP;
    const __half2* hp = (const __half2*)hs + (size_t)slice * n * 8 + fl;

    for (int base_e = 0; base_e < scnt; base_e += 256) {
        int e = base_e + tid;
        eb[tid] = (e < scnt) ? tp[e] : 0u;
        __syncthreads();
        int m = scnt - base_e; if (m > 256) m = 256;
        unsigned int v[8]; __half2 g[8];
        #pragma unroll
        for (int u = 0; u < 8; ++u) {
            int k = grp + u * 32;
            v[u] = (k < m) ? eb[k] : 0xFFFFFFFFu;
            int srcn = (v[u] != 0xFFFFFFFFu) ? (int)(v[u] >> BKT_SHIFT) : 0;
            g[u] = hp[(size_t)srcn * 8];
        }
        #pragma unroll
        for (int u = 0; u < 8; ++u) {
            if (v[u] != 0xFFFFFFFFu) {
                float2 w = __half22float2(g[u]);
                int dl = (int)(v[u] & (BKT_G - 1));
                atomicAdd(&acc[dl][fl * 2],     w.x);
                atomicAdd(&acc[dl][fl * 2 + 1], w.y);
            }
        }
        __syncthreads();
    }

    // epilogue: node = b*128 + (tid>>1), features [off, off+8) of this slice
    const int nl = tid >> 1;
    const int node = b * BKT_G + nl;
    const int off = (tid & 1) * 8;
    if (node < n) {
        float d = dinv[node];
        const __half2* hr = (const __half2*)(hs + ((size_t)slice * n + node) * 16 + off);
        float o[8];
        #pragma unroll
        for (int k = 0; k < 4; ++k) {
            float2 self = __half22float2(hr[k]);
            o[k * 2]     = (acc[nl][off + k * 2]     + self.x) * d + bias[slice * 16 + off + k * 2];
            o[k * 2 + 1] = (acc[nl][off + k * 2 + 1] + self.y) * d + bias[slice * 16 + off + k * 2 + 1];
        }
        if (do_relu) {
            #pragma unroll
            for (int k = 0; k < 8; ++k) o[k] = fmaxf(o[k], 0.f);
        }
        if (outf) {
            float4 t0 = {o[0], o[1], o[2], o[3]};
            float4 t1 = {o[4], o[5], o[6], o[7]};
            float4* op = (float4*)(outf + (size_t)node * FEAT + slice * 16 + off);
            op[0] = t0; op[1] = t1;
        } else {
            ushort4 h0, h1, l0, l1;
            h0.x = f2bf(o[0]); l0.x = f2bf(o[0] - bf2f(h0.x));
            h0.y = f2bf(o[1]); l0.y = f2bf(o[1] - bf2f(h0.y));
            h0.z = f2bf(o[2]); l0.z = f2bf(o[2] - bf2f(h0.z));
            h0.w = f2bf(o[3]); l0.w = f2bf(o[3] - bf2f(h0.w));
            h1.x = f2bf(o[4]); l1.x = f2bf(o[4] - bf2f(h1.x));
            h1.y = f2bf(o[5]); l1.y = f2bf(o[5] - bf2f(h1.y));
            h1.z = f2bf(o[6]); l1.z = f2bf(o[6] - bf2f(h1.z));
            h1.w = f2bf(o[7]); l1.w = f2bf(o[7] - bf2f(h1.w));
            const size_t sb = ((size_t)slice * n + node) * 16 + off;
            *(ushort4*)&outh[sb]     = h0;
            *(ushort4*)&outh[sb + 4] = h1;
            *(ushort4*)&outl[sb]     = l0;
            *(ushort4*)&outl[sb + 4] = l1;
        }
    }
}

// ---- launch ----------------------------------------------------------------

static inline size_t align256(size_t x) { return (x + 255) & ~(size_t)255; }

extern "C" void kernel_launch(void* const* d_in, const int* in_sizes, int n_in,
                              void* d_out, int out_size, void* d_ws, size_t ws_size,
                              hipStream_t stream) {
    const float* x  = (const float*)d_in[0];
    const int*   ei = (const int*)d_in[1];
    const float* W1 = (const float*)d_in[2];
    const float* b1 = (const float*)d_in[3];
    const float* W2 = (const float*)d_in[4];
    const float* b2 = (const float*)d_in[5];
    const float* W3 = (const float*)d_in[6];
    const float* b3 = (const float*)d_in[7];

    int n = in_sizes[0] / FEAT;      // 100000
    int E = in_sizes[1] / 2;         // 1600000
    const int* src = ei;
    const int* dst = ei + E;
    int NB = (n + BKT_G - 1) >> BKT_SHIFT;   // 782 buckets (n <= 131072 assumed)

    // workspace carve-up (~36 MB)
    char* w = (char*)d_ws;
    int* bcur    = (int*)w;                    w += align256((size_t)MAX_NB * 4);
    float* dinv  = (float*)w;                  w += align256((size_t)n * 4);
    unsigned int* tmp = (unsigned int*)w;      w += align256((size_t)NB * BCAP * 4);
    __half* hs   = (__half*)w;                 w += align256((size_t)n * FEAT * 2);
    unsigned short* wth = (unsigned short*)w;  w += align256((size_t)3 * 16384 * 2);
    unsigned short* wtl = (unsigned short*)w;  w += align256((size_t)3 * 16384 * 2);

    // sliced bf16 activation planes live in d_out (n*FEAT*4 bytes total)
    unsigned short* xh = (unsigned short*)d_out;
    unsigned short* xl = xh + (size_t)n * FEAT;

    binit_kernel<<<(NB + 255) / 256, 256, 0, stream>>>(bcur, NB);
    bucket_scatter_kernel<<<(E + SC_EPB - 1) / SC_EPB, 256, 0, stream>>>(src, dst, bcur, tmp, E, NB);
    dinv_wprep_kernel<<<NB + 192, 256, 0, stream>>>(bcur, tmp, dinv, n, NB,
                                                    W1, W2, W3, wth, wtl);

    const int gemm_grid = (n + 127) / 128;
    const int agg_grid = NB * 8;
    for (int L = 0; L < 3; ++L) {
        const float* bb = (L == 0) ? b1 : (L == 1) ? b2 : b3;

        if (L == 0) {
            gemm_mfma<true><<<gemm_grid, 512, 0, stream>>>(x, nullptr, nullptr,
                                                           wth, wtl, dinv, hs, n);
        } else {
            gemm_mfma<false><<<gemm_grid, 512, 0, stream>>>(nullptr, xh, xl,
                                                            wth + (size_t)L * 16384,
                                                            wtl + (size_t)L * 16384,
                                                            dinv, hs, n);
        }
        if (L < 2) {
            agg_kernel<<<agg_grid, 256, 0, stream>>>(hs, tmp, bcur, dinv, bb,
                                                     nullptr, xh, xl, n, 1);
        } else {
            agg_kernel<<<agg_grid, 256, 0, stream>>>(hs, tmp, bcur, dinv, bb,
                                                     (float*)d_out, nullptr, nullptr, n, 0);
        }
    }
}

// Round 10
// 401.769 us; speedup vs baseline: 8.4117x; 8.4117x over previous
//
#include <hip/hip_runtime.h>
#include <hip/hip_bf16.h>
#include <hip/hip_fp16.h>

#define FEAT 128

typedef __attribute__((ext_vector_type(8))) short short8;
typedef __attribute__((ext_vector_type(4))) float f32x4;

static __device__ __forceinline__ unsigned short f2bf(float f) {
    unsigned int u = __float_as_uint(f);
    unsigned int r = (u + 0x7fffu + ((u >> 16) & 1u)) >> 16;
    return (unsigned short)r;
}
static __device__ __forceinline__ float bf2f(unsigned short b) {
    return __uint_as_float(((unsigned int)b) << 16);
}

// ---- CSR build -------------------------------------------------------------
// Fixed-capacity bucket scatter: binit(bcur[b]=b*CAP) -> bucket_scatter ->
// bscan(782 totals, merged with wprep) -> bucket_fill2 (LDS hist + scan ->
// dinv, indptr, ssrc).
// NOTE (r8/r9 post-mortem): feature-sliced L2-resident gather layouts were
// tried twice — r8 (node-per-8-lane-group: FETCH 195->86 MB but 94 us from
// divergence + thin gathers) and r9 (edge-centric LDS atomics: 1075 us,
// 800K bank conflicts). The r4 structure below is the measured optimum; its
// ~4 TB/s effective rate on random 256 B gathers is the pattern ceiling.

#define BKT_SHIFT 7
#define BKT_G 128
#define MAX_NB 1024
#define BCAP 4096
#define SC_T 32
#define SC_EPB (256 * SC_T)   // 8192 edges per block

__global__ void binit_kernel(int* __restrict__ bcur, int NB) {
    int b = blockIdx.x * 256 + threadIdx.x;
    if (b < NB) bcur[b] = b * BCAP;
}

__global__ __launch_bounds__(256)
void bucket_scatter_kernel(const int* __restrict__ src, const int* __restrict__ dst,
                           int* __restrict__ bcur, unsigned int* __restrict__ tmp,
                           int E, int NB) {
    __shared__ int hist[MAX_NB];
    const int tid = threadIdx.x;
    const int ebase = blockIdx.x * SC_EPB;

    for (int i = tid; i < NB; i += 256) hist[i] = 0;
    __syncthreads();

    unsigned int pk[SC_T];    // packed (src,dst_local)
    unsigned int meta[SC_T];  // (bucket<<16) | local_rank ; 0xFFFFFFFF = invalid
    #pragma unroll
    for (int j = 0; j < SC_T; ++j) {
        int e = ebase + j * 256 + tid;
        if (e < E) {
            int s = src[e], d = dst[e];
            int b = d >> BKT_SHIFT;
            pk[j] = ((unsigned int)s << BKT_SHIFT) | (unsigned int)(d & (BKT_G - 1));
            int r = atomicAdd(&hist[b], 1);
            meta[j] = ((unsigned int)b << 16) | (unsigned int)r;
        } else {
            meta[j] = 0xFFFFFFFFu;
        }
    }
    __syncthreads();

    // one global atomic per (block,bucket); stash base back into hist
    for (int b = tid; b < NB; b += 256) {
        int c = hist[b];
        if (c > 0) hist[b] = atomicAdd(&bcur[b], c);
    }
    __syncthreads();

    #pragma unroll
    for (int j = 0; j < SC_T; ++j) {
        if (meta[j] != 0xFFFFFFFFu) {
            int b = meta[j] >> 16;
            int r = (int)(meta[j] & 0xFFFFu);
            tmp[hist[b] + r] = pk[j];
        }
    }
}

// block 0: exclusive scan of bucket totals (bcur[b]-b*CAP) -> bbase[0..NB],
// indptr[n]=E. blocks 1..48: weight prep (transpose + bf16 hi/lo split).
__global__ __launch_bounds__(1024)
void bscan_wprep_kernel(const int* __restrict__ bcur, int* __restrict__ bbase,
                        int* __restrict__ indptr, int n, int NB, int E,
                        const float* __restrict__ W1, const float* __restrict__ W2,
                        const float* __restrict__ W3, unsigned short* __restrict__ wth,
                        unsigned short* __restrict__ wtl) {
    if (blockIdx.x == 0) {
        __shared__ int swave[16];
        int tid = threadIdx.x, lane = tid & 63, wid = tid >> 6;
        int c = (tid < NB) ? (bcur[tid] - tid * BCAP) : 0;
        int x = c;
        #pragma unroll
        for (int off = 1; off < 64; off <<= 1) {
            int y = __shfl_up(x, off);
            if (lane >= off) x += y;
        }
        if (lane == 63) swave[wid] = x;
        __syncthreads();
        if (wid == 0 && lane < 16) {
            int s = swave[lane];
            #pragma unroll
            for (int off = 1; off < 16; off <<= 1) {
                int y = __shfl_up(s, off);
                if (lane >= off) s += y;
            }
            swave[lane] = s;
        }
        __syncthreads();
        int waveoff = (wid > 0) ? swave[wid - 1] : 0;
        if (tid <= NB) bbase[tid] = waveoff + x - c;   // exclusive prefix
        if (tid == 0) indptr[n] = E;
    } else {
        int idx = (blockIdx.x - 1) * 1024 + threadIdx.x;   // 3 * 16384 total
        if (idx < 3 * 16384) {
            int l = idx >> 14, t = idx & 16383;
            int nn = t >> 7, kk = t & 127;
            const float* W = (l == 0) ? W1 : (l == 1) ? W2 : W3;
            float v = W[kk * 128 + nn];
            unsigned short h = f2bf(v);
            wth[idx] = h;
            wtl[idx] = f2bf(v - bf2f(h));
        }
    }
}

// block b: count local dst in LDS, emit dinv+indptr, scan, scatter ssrc.
__global__ __launch_bounds__(256)
void bucket_fill2_kernel(const unsigned int* __restrict__ tmp, const int* __restrict__ bbase,
                         int* __restrict__ indptr, float* __restrict__ dinv,
                         int* __restrict__ ssrc, int n) {
    __shared__ int cnt[BKT_G];
    __shared__ int cur[BKT_G];
    __shared__ int wtot;
    const int tid = threadIdx.x;
    const int b = blockIdx.x;
    const int nodebase = b * BKT_G;
    const int base_g = bbase[b];
    const int scnt = bbase[b + 1] - base_g;
    const unsigned int* tp = tmp + (size_t)b * BCAP;

    if (tid < BKT_G) cnt[tid] = 0;
    __syncthreads();
    for (int e = tid; e < scnt; e += 256)
        atomicAdd(&cnt[tp[e] & (BKT_G - 1)], 1);
    __syncthreads();

    int c = 0, x = 0;
    if (tid < BKT_G) {
        int lane = tid & 63;
        c = cnt[tid];
        x = c;
        #pragma unroll
        for (int off = 1; off < 64; off <<= 1) {
            int y = __shfl_up(x, off);
            if (lane >= off) x += y;
        }
    }
    if (tid == 63) wtot = x;   // wave0 inclusive total
    __syncthreads();
    if (tid < BKT_G) {
        int excl = x - c + ((tid >= 64) ? wtot : 0);
        int node = nodebase + tid;
        if (node < n) {
            dinv[node]   = rsqrtf((float)(c + 1));
            indptr[node] = base_g + excl;
        }
        cur[tid] = base_g + excl;
    }
    __syncthreads();
    for (int e = tid; e < scnt; e += 256) {
        unsigned int v = tp[e];
        int pos = atomicAdd(&cur[v & (BKT_G - 1)], 1);
        ssrc[pos] = (int)(v >> BKT_SHIFT);
    }
}

// ---- GEMM (split-bf16 MFMA, B staged in LDS): hs = (in @ W) * dinv, fp16 out
// 128-row M-tile, 512 threads (8 waves), 69.6 KB LDS -> 2 blocks/CU = 16
// waves/CU. Layer 1 reads f32 x directly and splits to bf16 hi/lo in-register
// (bit-identical to a separate split pass; saves its 102 MB of traffic).

template <bool F32IN>
__global__ __launch_bounds__(512)
void gemm_mfma(const float* __restrict__ xf, const unsigned short* __restrict__ xh,
               const unsigned short* __restrict__ xl,
               const unsigned short* __restrict__ wth, const unsigned short* __restrict__ wtl,
               const float* __restrict__ dinv, __half* __restrict__ hs, int n) {
    __shared__ unsigned short bh[128][136];
    __shared__ unsigned short bl[128][136];

    const int tid = threadIdx.x;
    const int wave = tid >> 6, lane = tid & 63;
    const int rowbase = blockIdx.x * 128 + wave * 16;
    const int m = lane & 15, kg = lane >> 4;

    // stage B: 512 threads, 128 B each. plane p = tid>>8 (0=hi,1=lo)
    {
        const int p = tid >> 8, t = tid & 255;
        const int n0 = t >> 1, kk0 = (t & 1) * 64;
        const unsigned short* g = (p ? wtl : wth) + (size_t)n0 * FEAT + kk0;
        unsigned short (*dstp)[136] = p ? bl : bh;
        #pragma unroll
        for (int j = 0; j < 8; ++j)
            *(short8*)&dstp[n0][kk0 + j * 8] = *(const short8*)(g + j * 8);
    }

    // A fragments (loaded while staging is in flight)
    int arow = rowbase + m;
    if (arow > n - 1) arow = n - 1;          // clamp; clamped rows never stored
    short8 avh[4], avl[4];
    if constexpr (F32IN) {
        const float* ap = xf + (size_t)arow * FEAT + kg * 8;
        #pragma unroll
        for (int s = 0; s < 4; ++s) {
            float4 f0 = *(const float4*)(ap + s * 32);
            float4 f1 = *(const float4*)(ap + s * 32 + 4);
            float fv[8] = {f0.x, f0.y, f0.z, f0.w, f1.x, f1.y, f1.z, f1.w};
            short8 h, l;
            #pragma unroll
            for (int k = 0; k < 8; ++k) {
                unsigned short hb = f2bf(fv[k]);
                h[k] = (short)hb;
                l[k] = (short)f2bf(fv[k] - bf2f(hb));
            }
            avh[s] = h; avl[s] = l;
        }
    } else {
        const size_t aoff = (size_t)arow * FEAT + kg * 8;
        #pragma unroll
        for (int s = 0; s < 4; ++s) {
            avh[s] = *(const short8*)(xh + aoff + s * 32);
            avl[s] = *(const short8*)(xl + aoff + s * 32);
        }
    }

    __syncthreads();

    f32x4 acc[8];
    #pragma unroll
    for (int t = 0; t < 8; ++t) acc[t] = (f32x4){0.f, 0.f, 0.f, 0.f};

    #pragma unroll 2
    for (int t = 0; t < 8; ++t) {
        #pragma unroll
        for (int s = 0; s < 4; ++s) {
            short8 bvh = *(const short8*)&bh[t * 16 + m][s * 32 + kg * 8];
            short8 bvl = *(const short8*)&bl[t * 16 + m][s * 32 + kg * 8];
            acc[t] = __builtin_amdgcn_mfma_f32_16x16x32_bf16(avh[s], bvh, acc[t], 0, 0, 0);
            acc[t] = __builtin_amdgcn_mfma_f32_16x16x32_bf16(avh[s], bvl, acc[t], 0, 0, 0);
            acc[t] = __builtin_amdgcn_mfma_f32_16x16x32_bf16(avl[s], bvh, acc[t], 0, 0, 0);
        }
    }

    const int col = lane & 15, rb = (lane >> 4) * 4;
    #pragma unroll
    for (int r = 0; r < 4; ++r) {
        int row = rowbase + rb + r;
        if (row < n) {
            float d = dinv[row];
            __half* hrow = hs + (size_t)row * FEAT;
            #pragma unroll
            for (int t = 0; t < 8; ++t)
                hrow[t * 16 + col] = __float2half(acc[t][r] * d);
        }
    }
}

// ---- aggregation: out = act( dinv[i]*(hs[i] + sum hs[src]) + b ) -----------
// Round-4 form (measured optimum: 63.1-63.8 us): one node per wave, scalar-
// pipe indptr/ssrc via readfirstlane, 8 coalesced 256 B gathers in flight,
// 4 register accumulators. dinv/bias hoisted ahead of the edge loop.

__global__ __launch_bounds__(256)
void agg_kernel(const __half* __restrict__ hs, const int* __restrict__ indptr,
                const int* __restrict__ ssrc, const float* __restrict__ dinv,
                const float* __restrict__ bias, float* __restrict__ outf,
                unsigned short* __restrict__ outh, unsigned short* __restrict__ outl,
                int n, int do_relu) {
    int wid = threadIdx.x >> 6, lane = threadIdx.x & 63;
    int node = blockIdx.x * 4 + wid;
    if (node >= n) return;
    node = __builtin_amdgcn_readfirstlane(node);

    const __half2* hs2 = (const __half2*)hs;
    float d = dinv[node];
    float2 bv = ((const float2*)bias)[lane];
    float2 a0 = __half22float2(hs2[(size_t)node * 64 + lane]);  // self-loop term
    float2 a1 = {0.f, 0.f}, a2 = {0.f, 0.f}, a3 = {0.f, 0.f};

    int start = __builtin_amdgcn_readfirstlane(indptr[node]);
    int end   = __builtin_amdgcn_readfirstlane(indptr[node + 1]);
    const int* sp = ssrc + start;
    int cnt = end - start;

    int j = 0;
    for (; j + 8 <= cnt; j += 8) {
        int s0 = __builtin_amdgcn_readfirstlane(sp[j + 0]);
        int s1 = __builtin_amdgcn_readfirstlane(sp[j + 1]);
        int s2 = __builtin_amdgcn_readfirstlane(sp[j + 2]);
        int s3 = __builtin_amdgcn_readfirstlane(sp[j + 3]);
        int s4 = __builtin_amdgcn_readfirstlane(sp[j + 4]);
        int s5 = __builtin_amdgcn_readfirstlane(sp[j + 5]);
        int s6 = __builtin_amdgcn_readfirstlane(sp[j + 6]);
        int s7 = __builtin_amdgcn_readfirstlane(sp[j + 7]);
        float2 v0 = __half22float2(hs2[(size_t)s0 * 64 + lane]);
        float2 v1 = __half22float2(hs2[(size_t)s1 * 64 + lane]);
        float2 v2 = __half22float2(hs2[(size_t)s2 * 64 + lane]);
        float2 v3 = __half22float2(hs2[(size_t)s3 * 64 + lane]);
        float2 v4 = __half22float2(hs2[(size_t)s4 * 64 + lane]);
        float2 v5 = __half22float2(hs2[(size_t)s5 * 64 + lane]);
        float2 v6 = __half22float2(hs2[(size_t)s6 * 64 + lane]);
        float2 v7 = __half22float2(hs2[(size_t)s7 * 64 + lane]);
        a0.x += v0.x; a0.y += v0.y;
        a1.x += v1.x; a1.y += v1.y;
        a2.x += v2.x; a2.y += v2.y;
        a3.x += v3.x; a3.y += v3.y;
        a0.x += v4.x; a0.y += v4.y;
        a1.x += v5.x; a1.y += v5.y;
        a2.x += v6.x; a2.y += v6.y;
        a3.x += v7.x; a3.y += v7.y;
    }
    for (; j + 2 <= cnt; j += 2) {
        int s0 = __builtin_amdgcn_readfirstlane(sp[j + 0]);
        int s1 = __builtin_amdgcn_readfirstlane(sp[j + 1]);
        float2 v0 = __half22float2(hs2[(size_t)s0 * 64 + lane]);
        float2 v1 = __half22float2(hs2[(size_t)s1 * 64 + lane]);
        a0.x += v0.x; a0.y += v0.y;
        a1.x += v1.x; a1.y += v1.y;
    }
    if (j < cnt) {
        int s = __builtin_amdgcn_readfirstlane(sp[j]);
        float2 v = __half22float2(hs2[(size_t)s * 64 + lane]);
        a2.x += v.x; a2.y += v.y;
    }

    float ox = ((a0.x + a1.x) + (a2.x + a3.x)) * d + bv.x;
    float oy = ((a0.y + a1.y) + (a2.y + a3.y)) * d + bv.y;
    if (do_relu) { ox = fmaxf(ox, 0.f); oy = fmaxf(oy, 0.f); }

    if (outf) {
        float2 o; o.x = ox; o.y = oy;
        ((float2*)outf)[(size_t)node * 64 + lane] = o;
    } else {
        ushort2 h, l;
        h.x = f2bf(ox); l.x = f2bf(ox - bf2f(h.x));
        h.y = f2bf(oy); l.y = f2bf(oy - bf2f(h.y));
        ((ushort2*)outh)[(size_t)node * 64 + lane] = h;
        ((ushort2*)outl)[(size_t)node * 64 + lane] = l;
    }
}

// ---- launch ----------------------------------------------------------------

static inline size_t align256(size_t x) { return (x + 255) & ~(size_t)255; }

extern "C" void kernel_launch(void* const* d_in, const int* in_sizes, int n_in,
                              void* d_out, int out_size, void* d_ws, size_t ws_size,
                              hipStream_t stream) {
    const float* x  = (const float*)d_in[0];
    const int*   ei = (const int*)d_in[1];
    const float* W1 = (const float*)d_in[2];
    const float* b1 = (const float*)d_in[3];
    const float* W2 = (const float*)d_in[4];
    const float* b2 = (const float*)d_in[5];
    const float* W3 = (const float*)d_in[6];
    const float* b3 = (const float*)d_in[7];

    int n = in_sizes[0] / FEAT;      // 100000
    int E = in_sizes[1] / 2;         // 1600000
    const int* src = ei;
    const int* dst = ei + E;
    int NB = (n + BKT_G - 1) >> BKT_SHIFT;   // 782 buckets (n <= 131072 assumed)

    // workspace carve-up (~34 MB)
    char* w = (char*)d_ws;
    int* indptr  = (int*)w;                    w += align256((size_t)(n + 1) * 4);
    int* bcur    = (int*)w;                    w += align256((size_t)MAX_NB * 4);
    int* bbase   = (int*)w;                    w += align256((size_t)(MAX_NB + 1) * 4);
    float* dinv  = (float*)w;                  w += align256((size_t)n * 4);
    int* ssrc    = (int*)w;                    w += align256((size_t)E * 4);
    __half* hs   = (__half*)w;                 w += align256((size_t)n * FEAT * 2);
    unsigned short* wth = (unsigned short*)w;  w += align256((size_t)3 * 16384 * 2);
    unsigned short* wtl = (unsigned short*)w;  w += align256((size_t)3 * 16384 * 2);

    // bucket-strided packed edges alias hs (NB*BCAP*4 = 12.8 MB <= 25.6 MB;
    // tmp is dead before the first gemm writes hs)
    unsigned int* tmp = (unsigned int*)hs;

    // split activations live in d_out (exactly n*FEAT*4 bytes = two bf16 planes)
    unsigned short* xh = (unsigned short*)d_out;
    unsigned short* xl = xh + (size_t)n * FEAT;

    binit_kernel<<<(NB + 255) / 256, 256, 0, stream>>>(bcur, NB);
    bucket_scatter_kernel<<<(E + SC_EPB - 1) / SC_EPB, 256, 0, stream>>>(src, dst, bcur, tmp, E, NB);
    bscan_wprep_kernel<<<49, 1024, 0, stream>>>(bcur, bbase, indptr, n, NB, E,
                                                W1, W2, W3, wth, wtl);
    bucket_fill2_kernel<<<NB, 256, 0, stream>>>(tmp, bbase, indptr, dinv, ssrc, n);

    const int gemm_grid = (n + 127) / 128;
    for (int L = 0; L < 3; ++L) {
        const float* bb = (L == 0) ? b1 : (L == 1) ? b2 : b3;

        if (L == 0) {
            gemm_mfma<true><<<gemm_grid, 512, 0, stream>>>(x, nullptr, nullptr,
                                                           wth, wtl, dinv, hs, n);
        } else {
            gemm_mfma<false><<<gemm_grid, 512, 0, stream>>>(nullptr, xh, xl,
                                                            wth + (size_t)L * 16384,
                                                            wtl + (size_t)L * 16384,
                                                            dinv, hs, n);
        }
        if (L < 2) {
            agg_kernel<<<(n + 3) / 4, 256, 0, stream>>>(hs, indptr, ssrc, dinv, bb,
                                                        nullptr, xh, xl, n, 1);
        } else {
            agg_kernel<<<(n + 3) / 4, 256, 0, stream>>>(hs, indptr, ssrc, dinv, bb,
                                                        (float*)d_out, nullptr, nullptr, n, 0);
        }
    }
}